// Round 16
// baseline (294.504 us; speedup 1.0000x reference)
//
#include <hip/hip_runtime.h>
#include <hip/hip_bf16.h>
#include <cstdint>

#define BATCH 32
#define CIN   256
#define COUT  256
#define HW    56
#define NEXP  8
#define HP    58

typedef __bf16 bf16x8 __attribute__((ext_vector_type(8)));
typedef float  f32x4  __attribute__((ext_vector_type(4)));
typedef unsigned short u16x8 __attribute__((ext_vector_type(8)));

static __device__ __forceinline__ unsigned short f32_to_bf16(float f) {
    uint32_t u = __builtin_bit_cast(uint32_t, f);
    return (unsigned short)((u + 0x7FFFu + ((u >> 16) & 1u)) >> 16);
}

// ---- x fp32 [b][i][56][56] -> xTp bf16 [b][58][58][i] (zero halo) + GAP row-sums ----
__global__ void transpose_kernel(const float* __restrict__ x, unsigned short* __restrict__ xtp,
                                 float* __restrict__ gap) {
    int hp = blockIdx.x;
    int ib = blockIdx.y;
    int b  = blockIdx.z;
    int t  = threadIdx.x;
    __shared__ float tile[32][57];
    bool in_h = (hp >= 1 && hp <= HW);
    if (in_h) {
        const float* src = x + (((size_t)b * CIN + ib * 32) * HW + (hp - 1)) * HW;
        for (int idx = t; idx < 32 * HW; idx += 256) {
            int il = idx / HW, w = idx - il * HW;
            tile[il][w] = src[(size_t)il * (HW * HW) + w];
        }
    }
    __syncthreads();
    unsigned short* dst = xtp + (((size_t)b * HP + hp) * HP) * CIN + ib * 32;
    for (int idx = t; idx < HP * 32; idx += 256) {
        int wp = idx >> 5, il = idx & 31;
        float v = 0.f;
        if (in_h && wp >= 1 && wp <= HW) v = tile[il][wp - 1];
        dst[(size_t)wp * CIN + il] = f32_to_bf16(v);
    }
    if (in_h) {
        int c = t >> 3, j0 = t & 7;
        float s = 0.f;
        for (int j = j0; j < HW; j += 8) s += tile[c][j];
        s += __shfl_down(s, 4, 8);
        s += __shfl_down(s, 2, 8);
        s += __shfl_down(s, 1, 8);
        if (j0 == 0) atomicAdd(&gap[b * CIN + ib * 32 + c], s);
    }
}

// ---- routing[b][e] = sigmoid(gapsum[b]·fc_w[e]/3136 + fc_b[e]) ----
__global__ void routing_kernel(const float* __restrict__ gap, const float* __restrict__ fcw,
                               const float* __restrict__ fcb, float* __restrict__ rout) {
    int t = threadIdx.x;
    int b = t >> 3, e = t & 7;
    const float* g = gap + b * CIN;
    const float* w = fcw + e * CIN;
    float z = 0.f;
    for (int c = 0; c < CIN; ++c) z += g[c] * w[c];
    z = z * (1.0f / 3136.0f) + fcb[e];
    rout[b * NEXP + e] = 1.f / (1.f + expf(-z));
}

// ---- cmb pages: [b][ib][r] of 8192 elems = [o(256)][k(32)] row-major ----
__global__ void combine_kernel(const float* __restrict__ kw, const float* __restrict__ rout,
                               unsigned short* __restrict__ cmb) {
    int o  = blockIdx.x;
    int bq = blockIdx.y;             // batch quarter
    int t  = threadIdx.x;            // channel i
    __shared__ float rs[BATCH][NEXP];
    __shared__ __align__(16) unsigned short sbuf[8][9][32];
    rs[t >> 3][t & 7] = rout[t];
    __syncthreads();
    float kv[NEXP][9];
    #pragma unroll
    for (int e = 0; e < NEXP; ++e) {
        const float* p = kw + (((size_t)e * COUT + o) * CIN + t) * 9;
        #pragma unroll
        for (int r = 0; r < 9; ++r) kv[e][r] = p[r];
    }
    int ib = t >> 5, il = t & 31;
    for (int bb = 0; bb < 8; ++bb) {
        int b = bq * 8 + bb;
        #pragma unroll
        for (int r = 0; r < 9; ++r) {
            float s = 0.f;
            #pragma unroll
            for (int e = 0; e < NEXP; ++e) s += rs[b][e] * kv[e][r];
            sbuf[ib][r][il] = f32_to_bf16(s);
        }
        __syncthreads();
        // 288 vector stores of 16B: sid -> (ib2, r, slot)
        for (int sid = t; sid < 288; sid += 256) {
            int ib2 = sid / 36, rem = sid % 36;
            int rr = rem >> 2, slot = rem & 3;
            size_t dst = (size_t)(b * 72 + ib2 * 9 + rr) * 8192 + o * 32 + slot * 8;
            *reinterpret_cast<u16x8*>(cmb + dst) =
                *reinterpret_cast<const u16x8*>(&sbuf[ib2][rr][slot * 8]);
        }
        __syncthreads();
    }
}

// ---- conv: 256 thr = 4 waves, each 64o x 112px (acc[4][7], 16x16x32 MFMA).
// Block = 256o x 112px (14h x 8w); 896 blocks; __launch_bounds__(256,2) = 2 blocks/CU.
// Register diet for 2 waves/SIMD: single af[4] set reloaded per r-step AFTER the MFMA
// cluster (WAR bounds pipeline depth), bv loaded per-nt inline, A addressed as uniform
// SGPR page base + one 32-bit lane offset.
// B: window 160 pos x 128B (8 slots of 16B), chunk q at slot q^(pos&7) via
//    inverse-swizzled global_load_lds SOURCE; read slot = lk^(pos&7) [~2.5-4cyc/read].
// Sync: raw s_barrier + counted vmcnt(4) per ib (af for next ib stays in flight;
// staging, older, is proven drained by the r>=1 af waits).
#define WBUF 20480

__global__ __launch_bounds__(256, 2)
void conv_kernel(const unsigned short* __restrict__ xtp, const unsigned short* __restrict__ cmb,
                 float* __restrict__ out) {
    __shared__ __align__(16) char lds[2 * WBUF];
    const int t = threadIdx.x, wave = t >> 6, l = t & 63;
    const int lr = l & 15, lk = l >> 4;

    // bijective XCD swizzle: 896 = 8 x 112
    int bid = blockIdx.x;
    int wg  = (bid & 7) * 112 + (bid >> 3);
    int b   = wg / 28, pt = wg - b * 28;
    int ty = pt / 7, tx = pt - ty * 7;
    int oh0 = ty * 14, ow0 = tx * 8;

    const unsigned short* xb = xtp + (size_t)b * (HP * HP * CIN);

    // staging: 1280 chunks of 16B = 20 groups of 64; chunk c: pos = c>>3, slot = c&7,
    // source chunk q = (slot ^ (pos&7)) & 3 (junk slots dup a valid chunk)
    int ws[5];
    #pragma unroll
    for (int k = 0; k < 5; ++k) {
        int c = (wave + 4 * k) * 64 + l;
        int pos = c >> 3, slot = c & 7;
        int q = (slot ^ (pos & 7)) & 3;
        int hh = pos / 10, ww = pos - hh * 10;
        ws[k] = ((oh0 + hh) * HP + (ow0 + ww)) * CIN + q * 8;
    }

    // A: uniform page base (SGPR) + per-lane 32-bit offset (1 VGPR)
    const char* cmbB = (const char*)cmb + (size_t)b * (72 * 16384);
    const int laneoff = wave * 4096 + lr * 64 + lk * 16;   // bytes within a 16KB page

#define STAGE_W(ibx, buf)                                                                   \
    { _Pragma("unroll")                                                                     \
      for (int k = 0; k < 5; ++k)                                                           \
          __builtin_amdgcn_global_load_lds(                                                 \
              (const __attribute__((address_space(1))) void*)(xb + ws[k] + (ibx) * 32),     \
              (__attribute__((address_space(3))) void*)(lds + (buf) + (wave + 4 * k) * 1024), \
              16, 0, 0); }

    f32x4 acc[4][7];
    #pragma unroll
    for (int m = 0; m < 4; ++m)
        #pragma unroll
        for (int nt = 0; nt < 7; ++nt) acc[m][nt] = (f32x4){0.f, 0.f, 0.f, 0.f};

    const int laneterm = (lr >> 3) * 10 + (lr & 7);

    // prologue: window ib=0 staged; A page 0 issued (newest); counted drain; barrier
    STAGE_W(0, 0);
    u16x8 af[4];
    #pragma unroll
    for (int m = 0; m < 4; ++m)
        af[m] = *reinterpret_cast<const u16x8*>(cmbB + laneoff + m * 1024);
    asm volatile("s_waitcnt vmcnt(4)" ::: "memory");   // staging (older) drained; af in flight
    __builtin_amdgcn_s_barrier();

    for (int ib = 0; ib < 8; ++ib) {
        if (ib < 7) STAGE_W(ib + 1, ((ib + 1) & 1) * WBUF);
        const char* curw = lds + (ib & 1) * WBUF;
        #pragma unroll
        for (int r = 0; r < 9; ++r) {
            const int s = ib * 9 + r;
            const int dh = r / 3, dw = r - (r / 3) * 3;
            __builtin_amdgcn_s_setprio(1);
            #pragma unroll
            for (int nt = 0; nt < 7; ++nt) {
                int pos = laneterm + nt * 20 + dh * 10 + dw;
                bf16x8 bv = *reinterpret_cast<const bf16x8*>(
                    curw + pos * 128 + ((lk ^ (pos & 7)) << 4));
                #pragma unroll
                for (int m = 0; m < 4; ++m)
                    acc[m][nt] = __builtin_amdgcn_mfma_f32_16x16x32_bf16(
                        __builtin_bit_cast(bf16x8, af[m]), bv, acc[m][nt], 0, 0, 0);
            }
            __builtin_amdgcn_s_setprio(0);
            // reload af for the next K-step AFTER the cluster (WAR bounds depth to 1)
            if (r < 8 || ib < 7) {
                const char* pb = cmbB + (size_t)(s + 1) * 16384;
                #pragma unroll
                for (int m = 0; m < 4; ++m)
                    af[m] = *reinterpret_cast<const u16x8*>(pb + laneoff + m * 1024);
            }
        }
        if (ib < 7) {
            // counted: the 4 newest (next ib's af) stay in flight; staging already drained.
            asm volatile("s_waitcnt vmcnt(4)" ::: "memory");
            __builtin_amdgcn_s_barrier();
        }
    }

    // epilogue: D col = lane&15 (px), row = lk*4 + reg (o)
    #pragma unroll
    for (int m = 0; m < 4; ++m)
        #pragma unroll
        for (int nt = 0; nt < 7; ++nt) {
            int oh = oh0 + nt * 2 + (lr >> 3), ow = ow0 + (lr & 7);
            #pragma unroll
            for (int reg = 0; reg < 4; ++reg) {
                int o = wave * 64 + m * 16 + lk * 4 + reg;
                out[(((size_t)b * COUT + o) * HW + oh) * HW + ow] = acc[m][nt][reg];
            }
        }
#undef STAGE_W
}

extern "C" void kernel_launch(void* const* d_in, const int* in_sizes, int n_in,
                              void* d_out, int out_size, void* d_ws, size_t ws_size,
                              hipStream_t stream) {
    const float* x   = (const float*)d_in[0];
    const float* kw  = (const float*)d_in[1];
    const float* fcw = (const float*)d_in[2];
    const float* fcb = (const float*)d_in[3];
    float* out = (float*)d_out;

    char* ws = (char*)d_ws;
    float* gap  = (float*)(ws + 0);                        //  32768 B
    float* rout = (float*)(ws + 32768);                    //   1024 B
    unsigned short* cmb = (unsigned short*)(ws + 33792);   // 37748736 B
    unsigned short* xtp = (unsigned short*)(ws + 33792 + 37748736); // 55107584 B

    hipMemsetAsync(gap, 0, BATCH * CIN * sizeof(float), stream);
    transpose_kernel<<<dim3(HP, 8, BATCH), 256, 0, stream>>>(x, xtp, gap);
    routing_kernel<<<1, 256, 0, stream>>>(gap, fcw, fcb, rout);
    combine_kernel<<<dim3(COUT, 4), 256, 0, stream>>>(kw, rout, cmb);
    conv_kernel<<<dim3(896), 256, 0, stream>>>(xtp, cmb, out);
}

// Round 17
// 219.811 us; speedup vs baseline: 1.3398x; 1.3398x over previous
//
#include <hip/hip_runtime.h>
#include <hip/hip_bf16.h>
#include <cstdint>

#define BATCH 32
#define CIN   256
#define COUT  256
#define HW    56
#define NEXP  8
#define HP    58

typedef __bf16 bf16x8 __attribute__((ext_vector_type(8)));
typedef float  f32x4  __attribute__((ext_vector_type(4)));
typedef unsigned short u16x8 __attribute__((ext_vector_type(8)));

static __device__ __forceinline__ unsigned short f32_to_bf16(float f) {
    uint32_t u = __builtin_bit_cast(uint32_t, f);
    return (unsigned short)((u + 0x7FFFu + ((u >> 16) & 1u)) >> 16);
}

// ---- x fp32 [b][i][56][56] -> xTp bf16 [b][58][58][i] (zero halo) + GAP row-sums ----
__global__ void transpose_kernel(const float* __restrict__ x, unsigned short* __restrict__ xtp,
                                 float* __restrict__ gap) {
    int hp = blockIdx.x;
    int ib = blockIdx.y;
    int b  = blockIdx.z;
    int t  = threadIdx.x;
    __shared__ float tile[32][57];
    bool in_h = (hp >= 1 && hp <= HW);
    if (in_h) {
        const float* src = x + (((size_t)b * CIN + ib * 32) * HW + (hp - 1)) * HW;
        for (int idx = t; idx < 32 * HW; idx += 256) {
            int il = idx / HW, w = idx - il * HW;
            tile[il][w] = src[(size_t)il * (HW * HW) + w];
        }
    }
    __syncthreads();
    unsigned short* dst = xtp + (((size_t)b * HP + hp) * HP) * CIN + ib * 32;
    for (int idx = t; idx < HP * 32; idx += 256) {
        int wp = idx >> 5, il = idx & 31;
        float v = 0.f;
        if (in_h && wp >= 1 && wp <= HW) v = tile[il][wp - 1];
        dst[(size_t)wp * CIN + il] = f32_to_bf16(v);
    }
    if (in_h) {
        int c = t >> 3, j0 = t & 7;
        float s = 0.f;
        for (int j = j0; j < HW; j += 8) s += tile[c][j];
        s += __shfl_down(s, 4, 8);
        s += __shfl_down(s, 2, 8);
        s += __shfl_down(s, 1, 8);
        if (j0 == 0) atomicAdd(&gap[b * CIN + ib * 32 + c], s);
    }
}

// ---- routing[b][e] = sigmoid(gapsum[b]·fc_w[e]/3136 + fc_b[e]) ----
__global__ void routing_kernel(const float* __restrict__ gap, const float* __restrict__ fcw,
                               const float* __restrict__ fcb, float* __restrict__ rout) {
    int t = threadIdx.x;
    int b = t >> 3, e = t & 7;
    const float* g = gap + b * CIN;
    const float* w = fcw + e * CIN;
    float z = 0.f;
    for (int c = 0; c < CIN; ++c) z += g[c] * w[c];
    z = z * (1.0f / 3136.0f) + fcb[e];
    rout[b * NEXP + e] = 1.f / (1.f + expf(-z));
}

// ---- cmb pages: [b][ib][r] of 8192 elems = [o(256)][k(32)] row-major ----
__global__ void combine_kernel(const float* __restrict__ kw, const float* __restrict__ rout,
                               unsigned short* __restrict__ cmb) {
    int o  = blockIdx.x;
    int bq = blockIdx.y;             // batch quarter
    int t  = threadIdx.x;            // channel i
    __shared__ float rs[BATCH][NEXP];
    __shared__ __align__(16) unsigned short sbuf[8][9][32];
    rs[t >> 3][t & 7] = rout[t];
    __syncthreads();
    float kv[NEXP][9];
    #pragma unroll
    for (int e = 0; e < NEXP; ++e) {
        const float* p = kw + (((size_t)e * COUT + o) * CIN + t) * 9;
        #pragma unroll
        for (int r = 0; r < 9; ++r) kv[e][r] = p[r];
    }
    int ib = t >> 5, il = t & 31;
    for (int bb = 0; bb < 8; ++bb) {
        int b = bq * 8 + bb;
        #pragma unroll
        for (int r = 0; r < 9; ++r) {
            float s = 0.f;
            #pragma unroll
            for (int e = 0; e < NEXP; ++e) s += rs[b][e] * kv[e][r];
            sbuf[ib][r][il] = f32_to_bf16(s);
        }
        __syncthreads();
        // 288 vector stores of 16B: sid -> (ib2, r, slot)
        for (int sid = t; sid < 288; sid += 256) {
            int ib2 = sid / 36, rem = sid % 36;
            int rr = rem >> 2, slot = rem & 3;
            size_t dst = (size_t)(b * 72 + ib2 * 9 + rr) * 8192 + o * 32 + slot * 8;
            *reinterpret_cast<u16x8*>(cmb + dst) =
                *reinterpret_cast<const u16x8*>(&sbuf[ib2][rr][slot * 8]);
        }
        __syncthreads();
    }
}

// ---- conv: 512 thr = 8 waves (4 o-quarters x 2 px-halves).
// Block = 256o x 224px (28h x 8w); 448 blocks; 1 block/CU (75KB LDS) = 2 waves/SIMD.
// Wave: 64o x 112px, acc[4][7] (112 AGPR), 4 MFMA per ds_read.
// r-loop NOT unrolled (unroll 1) -> VGPR working set stays ~1 iteration (~100 regs).
// A: global->reg af[4], reloaded per r-step AFTER the MFMA cluster, SGPR page base.
// B: window 300 pos x 128B (8 slots of 16B), chunk q at slot q^(pos&7) via
//    inverse-swizzled global_load_lds SOURCE; read slot = lk^(pos&7).
// Sync: raw s_barrier + counted vmcnt(4) per ib.
#define WBUF 38400

__global__ __launch_bounds__(512, 1)
void conv_kernel(const unsigned short* __restrict__ xtp, const unsigned short* __restrict__ cmb,
                 float* __restrict__ out) {
    __shared__ __align__(16) char lds[2 * WBUF];
    const int t = threadIdx.x, wave = t >> 6, l = t & 63;
    const int lr = l & 15, lk = l >> 4;
    const int wm = wave >> 1, wn = wave & 1;

    // bijective XCD swizzle: 448 = 8 x 56
    int bid = blockIdx.x;
    int wg  = (bid & 7) * 56 + (bid >> 3);
    int b   = wg / 14, pt = wg - b * 14;
    int ty = pt / 7, tx = pt - ty * 7;
    int oh0 = ty * 28, ow0 = tx * 8;

    const unsigned short* xb = xtp + (size_t)b * (HP * HP * CIN);

    // staging: 2400 chunks of 16B (300 pos x 8 slots); chunk c: pos=c>>3, slot=c&7,
    // source chunk q = (slot ^ (pos&7)) & 3 (junk slots dup a valid chunk)
    int ws[5];
    #pragma unroll
    for (int k = 0; k < 5; ++k) {
        int c = k * 512 + t;
        int cc = (c < 2400) ? c : 0;
        int pos = cc >> 3, slot = cc & 7;
        int q = (slot ^ (pos & 7)) & 3;
        int hh = pos / 10, ww = pos - hh * 10;
        ws[k] = ((oh0 + hh) * HP + (ow0 + ww)) * CIN + q * 8;
    }

    // A: uniform page base (SGPR) + per-lane 32-bit offset
    const char* cmbB = (const char*)cmb + (size_t)b * (72 * 16384);
    const int laneoff = wm * 4096 + lr * 64 + lk * 16;   // bytes within a 16KB page

#define STAGE_W(ibx, buf)                                                                   \
    { _Pragma("unroll")                                                                     \
      for (int k = 0; k < 4; ++k)                                                           \
          __builtin_amdgcn_global_load_lds(                                                 \
              (const __attribute__((address_space(1))) void*)(xb + ws[k] + (ibx) * 32),     \
              (__attribute__((address_space(3))) void*)(lds + (buf) + (k * 8 + wave) * 1024), \
              16, 0, 0);                                                                    \
      if (4 * 512 + t < 2400)                                                               \
          __builtin_amdgcn_global_load_lds(                                                 \
              (const __attribute__((address_space(1))) void*)(xb + ws[4] + (ibx) * 32),     \
              (__attribute__((address_space(3))) void*)(lds + (buf) + (32 + wave) * 1024),  \
              16, 0, 0); }

    f32x4 acc[4][7];
    #pragma unroll
    for (int m = 0; m < 4; ++m)
        #pragma unroll
        for (int nt = 0; nt < 7; ++nt) acc[m][nt] = (f32x4){0.f, 0.f, 0.f, 0.f};

    const int laneterm = wn * 140 + (lr >> 3) * 10 + (lr & 7);

    // prologue: window ib=0 staged; A page 0 issued (newest); counted drain; barrier
    STAGE_W(0, 0);
    u16x8 af[4];
    #pragma unroll
    for (int m = 0; m < 4; ++m)
        af[m] = *reinterpret_cast<const u16x8*>(cmbB + laneoff + m * 1024);
    asm volatile("s_waitcnt vmcnt(4)" ::: "memory");   // staging (older) drained; af in flight
    __builtin_amdgcn_s_barrier();

    for (int ib = 0; ib < 8; ++ib) {
        if (ib < 7) STAGE_W(ib + 1, ((ib + 1) & 1) * WBUF);
        const char* curw = lds + (ib & 1) * WBUF;
        #pragma unroll 1
        for (int r = 0; r < 9; ++r) {
            const int s = ib * 9 + r;
            const int dh = r / 3, dw = r - dh * 3;
            const int posbase = laneterm + dh * 10 + dw;
            __builtin_amdgcn_s_setprio(1);
            #pragma unroll
            for (int nt = 0; nt < 7; ++nt) {
                int pos = posbase + nt * 20;
                bf16x8 bv = *reinterpret_cast<const bf16x8*>(
                    curw + pos * 128 + ((lk ^ (pos & 7)) << 4));
                #pragma unroll
                for (int m = 0; m < 4; ++m)
                    acc[m][nt] = __builtin_amdgcn_mfma_f32_16x16x32_bf16(
                        __builtin_bit_cast(bf16x8, af[m]), bv, acc[m][nt], 0, 0, 0);
            }
            __builtin_amdgcn_s_setprio(0);
            // reload af for the next K-step AFTER the cluster (WAR bounds depth to 1)
            if (s < 71) {
                const char* pb = cmbB + (size_t)(s + 1) * 16384;
                #pragma unroll
                for (int m = 0; m < 4; ++m)
                    af[m] = *reinterpret_cast<const u16x8*>(pb + laneoff + m * 1024);
            }
        }
        if (ib < 7) {
            // counted: the 4 newest (next ib's af) stay in flight; staging already drained.
            asm volatile("s_waitcnt vmcnt(4)" ::: "memory");
            __builtin_amdgcn_s_barrier();
        }
    }

    // epilogue: D col = lane&15 (px), row = lk*4 + reg (o)
    #pragma unroll
    for (int m = 0; m < 4; ++m)
        #pragma unroll
        for (int nt = 0; nt < 7; ++nt) {
            int oh = oh0 + wn * 14 + nt * 2 + (lr >> 3), ow = ow0 + (lr & 7);
            #pragma unroll
            for (int reg = 0; reg < 4; ++reg) {
                int o = wm * 64 + m * 16 + lk * 4 + reg;
                out[(((size_t)b * COUT + o) * HW + oh) * HW + ow] = acc[m][nt][reg];
            }
        }
#undef STAGE_W
}

extern "C" void kernel_launch(void* const* d_in, const int* in_sizes, int n_in,
                              void* d_out, int out_size, void* d_ws, size_t ws_size,
                              hipStream_t stream) {
    const float* x   = (const float*)d_in[0];
    const float* kw  = (const float*)d_in[1];
    const float* fcw = (const float*)d_in[2];
    const float* fcb = (const float*)d_in[3];
    float* out = (float*)d_out;

    char* ws = (char*)d_ws;
    float* gap  = (float*)(ws + 0);                        //  32768 B
    float* rout = (float*)(ws + 32768);                    //   1024 B
    unsigned short* cmb = (unsigned short*)(ws + 33792);   // 37748736 B
    unsigned short* xtp = (unsigned short*)(ws + 33792 + 37748736); // 55107584 B

    hipMemsetAsync(gap, 0, BATCH * CIN * sizeof(float), stream);
    transpose_kernel<<<dim3(HP, 8, BATCH), 256, 0, stream>>>(x, xtp, gap);
    routing_kernel<<<1, 256, 0, stream>>>(gap, fcw, fcb, rout);
    combine_kernel<<<dim3(COUT, 4), 256, 0, stream>>>(kw, rout, cmb);
    conv_kernel<<<dim3(448), 512, 0, stream>>>(xtp, cmb, out);
}

// Round 18
// 204.651 us; speedup vs baseline: 1.4391x; 1.0741x over previous
//
#include <hip/hip_runtime.h>
#include <hip/hip_bf16.h>
#include <cstdint>

#define BATCH 32
#define CIN   256
#define COUT  256
#define HW    56
#define NEXP  8
#define HP    58

typedef __bf16 bf16x8 __attribute__((ext_vector_type(8)));
typedef float  f32x4  __attribute__((ext_vector_type(4)));
typedef unsigned short u16x8 __attribute__((ext_vector_type(8)));

static __device__ __forceinline__ unsigned short f32_to_bf16(float f) {
    uint32_t u = __builtin_bit_cast(uint32_t, f);
    return (unsigned short)((u + 0x7FFFu + ((u >> 16) & 1u)) >> 16);
}

// ---- x fp32 [b][i][56][56] -> xTp bf16 [b][58][58][i] (zero halo) + GAP row-sums ----
__global__ void transpose_kernel(const float* __restrict__ x, unsigned short* __restrict__ xtp,
                                 float* __restrict__ gap) {
    int hp = blockIdx.x;
    int ib = blockIdx.y;
    int b  = blockIdx.z;
    int t  = threadIdx.x;
    __shared__ float tile[32][57];
    bool in_h = (hp >= 1 && hp <= HW);
    if (in_h) {
        const float* src = x + (((size_t)b * CIN + ib * 32) * HW + (hp - 1)) * HW;
        for (int idx = t; idx < 32 * HW; idx += 256) {
            int il = idx / HW, w = idx - il * HW;
            tile[il][w] = src[(size_t)il * (HW * HW) + w];
        }
    }
    __syncthreads();
    unsigned short* dst = xtp + (((size_t)b * HP + hp) * HP) * CIN + ib * 32;
    for (int idx = t; idx < HP * 32; idx += 256) {
        int wp = idx >> 5, il = idx & 31;
        float v = 0.f;
        if (in_h && wp >= 1 && wp <= HW) v = tile[il][wp - 1];
        dst[(size_t)wp * CIN + il] = f32_to_bf16(v);
    }
    if (in_h) {
        int c = t >> 3, j0 = t & 7;
        float s = 0.f;
        for (int j = j0; j < HW; j += 8) s += tile[c][j];
        s += __shfl_down(s, 4, 8);
        s += __shfl_down(s, 2, 8);
        s += __shfl_down(s, 1, 8);
        if (j0 == 0) atomicAdd(&gap[b * CIN + ib * 32 + c], s);
    }
}

// ---- routing[b][e] = sigmoid(gapsum[b]·fc_w[e]/3136 + fc_b[e]) ----
__global__ void routing_kernel(const float* __restrict__ gap, const float* __restrict__ fcw,
                               const float* __restrict__ fcb, float* __restrict__ rout) {
    int t = threadIdx.x;
    int b = t >> 3, e = t & 7;
    const float* g = gap + b * CIN;
    const float* w = fcw + e * CIN;
    float z = 0.f;
    for (int c = 0; c < CIN; ++c) z += g[c] * w[c];
    z = z * (1.0f / 3136.0f) + fcb[e];
    rout[b * NEXP + e] = 1.f / (1.f + expf(-z));
}

// ---- cmb pages: [b][ib][r] of 8192 elems = [o(256)][k(32)] row-major ----
__global__ void combine_kernel(const float* __restrict__ kw, const float* __restrict__ rout,
                               unsigned short* __restrict__ cmb) {
    int o  = blockIdx.x;
    int bq = blockIdx.y;             // batch quarter
    int t  = threadIdx.x;            // channel i
    __shared__ float rs[BATCH][NEXP];
    __shared__ __align__(16) unsigned short sbuf[8][9][32];
    rs[t >> 3][t & 7] = rout[t];
    __syncthreads();
    float kv[NEXP][9];
    #pragma unroll
    for (int e = 0; e < NEXP; ++e) {
        const float* p = kw + (((size_t)e * COUT + o) * CIN + t) * 9;
        #pragma unroll
        for (int r = 0; r < 9; ++r) kv[e][r] = p[r];
    }
    int ib = t >> 5, il = t & 31;
    for (int bb = 0; bb < 8; ++bb) {
        int b = bq * 8 + bb;
        #pragma unroll
        for (int r = 0; r < 9; ++r) {
            float s = 0.f;
            #pragma unroll
            for (int e = 0; e < NEXP; ++e) s += rs[b][e] * kv[e][r];
            sbuf[ib][r][il] = f32_to_bf16(s);
        }
        __syncthreads();
        // 288 vector stores of 16B: sid -> (ib2, r, slot)
        for (int sid = t; sid < 288; sid += 256) {
            int ib2 = sid / 36, rem = sid % 36;
            int rr = rem >> 2, slot = rem & 3;
            size_t dst = (size_t)(b * 72 + ib2 * 9 + rr) * 8192 + o * 32 + slot * 8;
            *reinterpret_cast<u16x8*>(cmb + dst) =
                *reinterpret_cast<const u16x8*>(&sbuf[ib2][rr][slot * 8]);
        }
        __syncthreads();
    }
}

// ---- conv: 512 thr = 8 waves (4 o-quarters x 2 px-halves).
// Block = 256o x 224px (28h x 8w); 448 blocks; 75KB LDS dbuf; 2 waves/SIMD.
// Wave: 64o x 112px, acc[4][7] (112 AGPR), 4 MFMA per ds_read.
// r-loop NOT unrolled -> VGPR working set ~1 iteration.
// A: af[4]/afn[4] REGISTER DOUBLE-BUFFER: loads for s+1 issue BEFORE the s cluster
//    (L2 latency hides under 28 MFMAs), copy af<-afn after (compiler-counted vmcnt).
// B: window 300 pos x 128B (8 slots of 16B), chunk q at slot q^(pos&7) via
//    inverse-swizzled global_load_lds SOURCE; read slot = lk^(pos&7).
// Sync: raw s_barrier + counted vmcnt per ib.
#define WBUF 38400

__global__ __launch_bounds__(512, 1)
void conv_kernel(const unsigned short* __restrict__ xtp, const unsigned short* __restrict__ cmb,
                 float* __restrict__ out) {
    __shared__ __align__(16) char lds[2 * WBUF];
    const int t = threadIdx.x, wave = t >> 6, l = t & 63;
    const int lr = l & 15, lk = l >> 4;
    const int wm = wave >> 1, wn = wave & 1;

    // bijective XCD swizzle: 448 = 8 x 56
    int bid = blockIdx.x;
    int wg  = (bid & 7) * 56 + (bid >> 3);
    int b   = wg / 14, pt = wg - b * 14;
    int ty = pt / 7, tx = pt - ty * 7;
    int oh0 = ty * 28, ow0 = tx * 8;

    const unsigned short* xb = xtp + (size_t)b * (HP * HP * CIN);

    // staging: 2400 chunks of 16B (300 pos x 8 slots); chunk c: pos=c>>3, slot=c&7,
    // source chunk q = (slot ^ (pos&7)) & 3 (junk slots dup a valid chunk)
    int ws[5];
    #pragma unroll
    for (int k = 0; k < 5; ++k) {
        int c = k * 512 + t;
        int cc = (c < 2400) ? c : 0;
        int pos = cc >> 3, slot = cc & 7;
        int q = (slot ^ (pos & 7)) & 3;
        int hh = pos / 10, ww = pos - hh * 10;
        ws[k] = ((oh0 + hh) * HP + (ow0 + ww)) * CIN + q * 8;
    }

    // A: uniform page base (SGPR) + per-lane 32-bit offset
    const char* cmbB = (const char*)cmb + (size_t)b * (72 * 16384);
    const int laneoff = wm * 4096 + lr * 64 + lk * 16;   // bytes within a 16KB page

#define STAGE_W(ibx, buf)                                                                   \
    { _Pragma("unroll")                                                                     \
      for (int k = 0; k < 4; ++k)                                                           \
          __builtin_amdgcn_global_load_lds(                                                 \
              (const __attribute__((address_space(1))) void*)(xb + ws[k] + (ibx) * 32),     \
              (__attribute__((address_space(3))) void*)(lds + (buf) + (k * 8 + wave) * 1024), \
              16, 0, 0);                                                                    \
      if (4 * 512 + t < 2400)                                                               \
          __builtin_amdgcn_global_load_lds(                                                 \
              (const __attribute__((address_space(1))) void*)(xb + ws[4] + (ibx) * 32),     \
              (__attribute__((address_space(3))) void*)(lds + (buf) + (32 + wave) * 1024),  \
              16, 0, 0); }

    f32x4 acc[4][7];
    #pragma unroll
    for (int m = 0; m < 4; ++m)
        #pragma unroll
        for (int nt = 0; nt < 7; ++nt) acc[m][nt] = (f32x4){0.f, 0.f, 0.f, 0.f};

    const int laneterm = wn * 140 + (lr >> 3) * 10 + (lr & 7);

    // prologue: window ib=0 staged; A page 0 issued (newest); counted drain; barrier
    STAGE_W(0, 0);
    u16x8 af[4];
    #pragma unroll
    for (int m = 0; m < 4; ++m)
        af[m] = *reinterpret_cast<const u16x8*>(cmbB + laneoff + m * 1024);
    asm volatile("s_waitcnt vmcnt(4)" ::: "memory");   // staging (older) drained; af in flight
    __builtin_amdgcn_s_barrier();

    for (int ib = 0; ib < 8; ++ib) {
        if (ib < 7) STAGE_W(ib + 1, ((ib + 1) & 1) * WBUF);
        const char* curw = lds + (ib & 1) * WBUF;
        #pragma unroll 1
        for (int r = 0; r < 9; ++r) {
            const int s = ib * 9 + r;
            const int dh = r / 3, dw = r - dh * 3;
            const int posbase = laneterm + dh * 10 + dw;
            // issue next K-step's A loads BEFORE the cluster: latency hides under MFMAs
            u16x8 afn[4];
            if (s < 71) {
                const char* pb = cmbB + (size_t)(s + 1) * 16384;
                #pragma unroll
                for (int m = 0; m < 4; ++m)
                    afn[m] = *reinterpret_cast<const u16x8*>(pb + laneoff + m * 1024);
            }
            __builtin_amdgcn_s_setprio(1);
            #pragma unroll
            for (int nt = 0; nt < 7; ++nt) {
                int pos = posbase + nt * 20;
                bf16x8 bv = *reinterpret_cast<const bf16x8*>(
                    curw + pos * 128 + ((lk ^ (pos & 7)) << 4));
                #pragma unroll
                for (int m = 0; m < 4; ++m)
                    acc[m][nt] = __builtin_amdgcn_mfma_f32_16x16x32_bf16(
                        __builtin_bit_cast(bf16x8, af[m]), bv, acc[m][nt], 0, 0, 0);
            }
            __builtin_amdgcn_s_setprio(0);
            if (s < 71) {
                #pragma unroll
                for (int m = 0; m < 4; ++m) af[m] = afn[m];   // compiler inserts vmcnt wait
            }
        }
        if (ib < 7) {
            // keep next ib's af in flight; staging retired long ago
            asm volatile("s_waitcnt vmcnt(4)" ::: "memory");
            __builtin_amdgcn_s_barrier();
        }
    }

    // epilogue: D col = lane&15 (px), row = lk*4 + reg (o)
    #pragma unroll
    for (int m = 0; m < 4; ++m)
        #pragma unroll
        for (int nt = 0; nt < 7; ++nt) {
            int oh = oh0 + wn * 14 + nt * 2 + (lr >> 3), ow = ow0 + (lr & 7);
            #pragma unroll
            for (int reg = 0; reg < 4; ++reg) {
                int o = wm * 64 + m * 16 + lk * 4 + reg;
                out[(((size_t)b * COUT + o) * HW + oh) * HW + ow] = acc[m][nt][reg];
            }
        }
#undef STAGE_W
}

extern "C" void kernel_launch(void* const* d_in, const int* in_sizes, int n_in,
                              void* d_out, int out_size, void* d_ws, size_t ws_size,
                              hipStream_t stream) {
    const float* x   = (const float*)d_in[0];
    const float* kw  = (const float*)d_in[1];
    const float* fcw = (const float*)d_in[2];
    const float* fcb = (const float*)d_in[3];
    float* out = (float*)d_out;

    char* ws = (char*)d_ws;
    float* gap  = (float*)(ws + 0);                        //  32768 B
    float* rout = (float*)(ws + 32768);                    //   1024 B
    unsigned short* cmb = (unsigned short*)(ws + 33792);   // 37748736 B
    unsigned short* xtp = (unsigned short*)(ws + 33792 + 37748736); // 55107584 B

    hipMemsetAsync(gap, 0, BATCH * CIN * sizeof(float), stream);
    transpose_kernel<<<dim3(HP, 8, BATCH), 256, 0, stream>>>(x, xtp, gap);
    routing_kernel<<<1, 256, 0, stream>>>(gap, fcw, fcb, rout);
    combine_kernel<<<dim3(COUT, 4), 256, 0, stream>>>(kw, rout, cmb);
    conv_kernel<<<dim3(448), 512, 0, stream>>>(xtp, cmb, out);
}

// Round 19
// 204.026 us; speedup vs baseline: 1.4435x; 1.0031x over previous
//
#include <hip/hip_runtime.h>
#include <hip/hip_bf16.h>
#include <cstdint>

#define BATCH 32
#define CIN   256
#define COUT  256
#define HW    56
#define NEXP  8
#define HP    58

typedef __bf16 bf16x8 __attribute__((ext_vector_type(8)));
typedef float  f32x4  __attribute__((ext_vector_type(4)));
typedef unsigned short u16x8 __attribute__((ext_vector_type(8)));

static __device__ __forceinline__ unsigned short f32_to_bf16(float f) {
    uint32_t u = __builtin_bit_cast(uint32_t, f);
    return (unsigned short)((u + 0x7FFFu + ((u >> 16) & 1u)) >> 16);
}

// ---- x fp32 [b][i][56][56] -> xTp bf16 [b][58][58][i] (zero halo) + GAP row-sums ----
__global__ void transpose_kernel(const float* __restrict__ x, unsigned short* __restrict__ xtp,
                                 float* __restrict__ gap) {
    int hp = blockIdx.x;
    int ib = blockIdx.y;
    int b  = blockIdx.z;
    int t  = threadIdx.x;
    __shared__ float tile[32][57];
    bool in_h = (hp >= 1 && hp <= HW);
    if (in_h) {
        const float* src = x + (((size_t)b * CIN + ib * 32) * HW + (hp - 1)) * HW;
        for (int idx = t; idx < 32 * HW; idx += 256) {
            int il = idx / HW, w = idx - il * HW;
            tile[il][w] = src[(size_t)il * (HW * HW) + w];
        }
    }
    __syncthreads();
    unsigned short* dst = xtp + (((size_t)b * HP + hp) * HP) * CIN + ib * 32;
    for (int idx = t; idx < HP * 32; idx += 256) {
        int wp = idx >> 5, il = idx & 31;
        float v = 0.f;
        if (in_h && wp >= 1 && wp <= HW) v = tile[il][wp - 1];
        dst[(size_t)wp * CIN + il] = f32_to_bf16(v);
    }
    if (in_h) {
        int c = t >> 3, j0 = t & 7;
        float s = 0.f;
        for (int j = j0; j < HW; j += 8) s += tile[c][j];
        s += __shfl_down(s, 4, 8);
        s += __shfl_down(s, 2, 8);
        s += __shfl_down(s, 1, 8);
        if (j0 == 0) atomicAdd(&gap[b * CIN + ib * 32 + c], s);
    }
}

// ---- routing[b][e] = sigmoid(gapsum[b]·fc_w[e]/3136 + fc_b[e]) ----
__global__ void routing_kernel(const float* __restrict__ gap, const float* __restrict__ fcw,
                               const float* __restrict__ fcb, float* __restrict__ rout) {
    int t = threadIdx.x;
    int b = t >> 3, e = t & 7;
    const float* g = gap + b * CIN;
    const float* w = fcw + e * CIN;
    float z = 0.f;
    for (int c = 0; c < CIN; ++c) z += g[c] * w[c];
    z = z * (1.0f / 3136.0f) + fcb[e];
    rout[b * NEXP + e] = 1.f / (1.f + expf(-z));
}

// ---- cmb pages: [b][ib][r] of 8192 elems = [o(256)][k(32)] row-major ----
__global__ void combine_kernel(const float* __restrict__ kw, const float* __restrict__ rout,
                               unsigned short* __restrict__ cmb) {
    int o  = blockIdx.x;
    int bq = blockIdx.y;             // batch quarter
    int t  = threadIdx.x;            // channel i
    __shared__ float rs[BATCH][NEXP];
    __shared__ __align__(16) unsigned short sbuf[8][9][32];
    rs[t >> 3][t & 7] = rout[t];
    __syncthreads();
    float kv[NEXP][9];
    #pragma unroll
    for (int e = 0; e < NEXP; ++e) {
        const float* p = kw + (((size_t)e * COUT + o) * CIN + t) * 9;
        #pragma unroll
        for (int r = 0; r < 9; ++r) kv[e][r] = p[r];
    }
    int ib = t >> 5, il = t & 31;
    for (int bb = 0; bb < 8; ++bb) {
        int b = bq * 8 + bb;
        #pragma unroll
        for (int r = 0; r < 9; ++r) {
            float s = 0.f;
            #pragma unroll
            for (int e = 0; e < NEXP; ++e) s += rs[b][e] * kv[e][r];
            sbuf[ib][r][il] = f32_to_bf16(s);
        }
        __syncthreads();
        // 288 vector stores of 16B: sid -> (ib2, r, slot)
        for (int sid = t; sid < 288; sid += 256) {
            int ib2 = sid / 36, rem = sid % 36;
            int rr = rem >> 2, slot = rem & 3;
            size_t dst = (size_t)(b * 72 + ib2 * 9 + rr) * 8192 + o * 32 + slot * 8;
            *reinterpret_cast<u16x8*>(cmb + dst) =
                *reinterpret_cast<const u16x8*>(&sbuf[ib2][rr][slot * 8]);
        }
        __syncthreads();
    }
}

// ---- conv: 256 thr = 4 waves (64o x 112px each, acc[4][7], 16x16x32 MFMA).
// Block = 256o x 112px (14h x 8w); 896 blocks; 40KB LDS dbuf -> 2 blocks/CU,
// mutually DESYNCED (no shared barrier): when one block's waves barrier, the
// sibling block's waves keep the matrix pipe fed.
// A: af/afn register double-buffer, loads for s+1 issued BEFORE the s cluster
//    (L2 latency hides under 28 MFMAs); SGPR page base + 1 VGPR lane offset.
// B: window 160 pos x 128B (8 slots of 16B), chunk q at slot q^(pos&7) via
//    inverse-swizzled global_load_lds SOURCE; read slot = lk^(pos&7).
// r-loop unroll 1 keeps VGPR ~96; 96 + 112 AGPR = 208 <= 256 @ (256,2): no spill.
// Sync: raw s_barrier + counted vmcnt(4) per ib.
#define WBUF 20480

__global__ __launch_bounds__(256, 2)
void conv_kernel(const unsigned short* __restrict__ xtp, const unsigned short* __restrict__ cmb,
                 float* __restrict__ out) {
    __shared__ __align__(16) char lds[2 * WBUF];
    const int t = threadIdx.x, wave = t >> 6, l = t & 63;
    const int lr = l & 15, lk = l >> 4;

    // bijective XCD swizzle: 896 = 8 x 112
    int bid = blockIdx.x;
    int wg  = (bid & 7) * 112 + (bid >> 3);
    int b   = wg / 28, pt = wg - b * 28;
    int ty = pt / 7, tx = pt - ty * 7;
    int oh0 = ty * 14, ow0 = tx * 8;

    const unsigned short* xb = xtp + (size_t)b * (HP * HP * CIN);

    // staging: 1280 chunks of 16B (160 pos x 8 slots); chunk c: pos=c>>3, slot=c&7,
    // source chunk q = (slot ^ (pos&7)) & 3 (junk slots dup a valid chunk)
    int ws[5];
    #pragma unroll
    for (int k = 0; k < 5; ++k) {
        int c = (wave + 4 * k) * 64 + l;
        int pos = c >> 3, slot = c & 7;
        int q = (slot ^ (pos & 7)) & 3;
        int hh = pos / 10, ww = pos - hh * 10;
        ws[k] = ((oh0 + hh) * HP + (ow0 + ww)) * CIN + q * 8;
    }

    // A: uniform page base (SGPR) + per-lane 32-bit offset
    const char* cmbB = (const char*)cmb + (size_t)b * (72 * 16384);
    const int laneoff = wave * 4096 + lr * 64 + lk * 16;   // bytes within a 16KB page

#define STAGE_W(ibx, buf)                                                                   \
    { _Pragma("unroll")                                                                     \
      for (int k = 0; k < 5; ++k)                                                           \
          __builtin_amdgcn_global_load_lds(                                                 \
              (const __attribute__((address_space(1))) void*)(xb + ws[k] + (ibx) * 32),     \
              (__attribute__((address_space(3))) void*)(lds + (buf) + (wave + 4 * k) * 1024), \
              16, 0, 0); }

    f32x4 acc[4][7];
    #pragma unroll
    for (int m = 0; m < 4; ++m)
        #pragma unroll
        for (int nt = 0; nt < 7; ++nt) acc[m][nt] = (f32x4){0.f, 0.f, 0.f, 0.f};

    const int laneterm = (lr >> 3) * 10 + (lr & 7);

    // prologue: window ib=0 staged; A page 0 issued (newest); counted drain; barrier
    STAGE_W(0, 0);
    u16x8 af[4];
    #pragma unroll
    for (int m = 0; m < 4; ++m)
        af[m] = *reinterpret_cast<const u16x8*>(cmbB + laneoff + m * 1024);
    asm volatile("s_waitcnt vmcnt(4)" ::: "memory");   // staging (older) drained; af in flight
    __builtin_amdgcn_s_barrier();

    for (int ib = 0; ib < 8; ++ib) {
        if (ib < 7) STAGE_W(ib + 1, ((ib + 1) & 1) * WBUF);
        const char* curw = lds + (ib & 1) * WBUF;
        #pragma unroll 1
        for (int r = 0; r < 9; ++r) {
            const int s = ib * 9 + r;
            const int dh = r / 3, dw = r - dh * 3;
            const int posbase = laneterm + dh * 10 + dw;
            // issue next K-step's A loads BEFORE the cluster: latency hides under MFMAs
            u16x8 afn[4];
            if (s < 71) {
                const char* pb = cmbB + (size_t)(s + 1) * 16384;
                #pragma unroll
                for (int m = 0; m < 4; ++m)
                    afn[m] = *reinterpret_cast<const u16x8*>(pb + laneoff + m * 1024);
            }
            __builtin_amdgcn_s_setprio(1);
            #pragma unroll
            for (int nt = 0; nt < 7; ++nt) {
                int pos = posbase + nt * 20;
                bf16x8 bv = *reinterpret_cast<const bf16x8*>(
                    curw + pos * 128 + ((lk ^ (pos & 7)) << 4));
                #pragma unroll
                for (int m = 0; m < 4; ++m)
                    acc[m][nt] = __builtin_amdgcn_mfma_f32_16x16x32_bf16(
                        __builtin_bit_cast(bf16x8, af[m]), bv, acc[m][nt], 0, 0, 0);
            }
            __builtin_amdgcn_s_setprio(0);
            if (s < 71) {
                #pragma unroll
                for (int m = 0; m < 4; ++m) af[m] = afn[m];   // compiler-counted vmcnt wait
            }
        }
        if (ib < 7) {
            // keep next ib's af in flight; staging (older) fully retired by now
            asm volatile("s_waitcnt vmcnt(4)" ::: "memory");
            __builtin_amdgcn_s_barrier();
        }
    }

    // epilogue: D col = lane&15 (px), row = lk*4 + reg (o)
    #pragma unroll
    for (int m = 0; m < 4; ++m)
        #pragma unroll
        for (int nt = 0; nt < 7; ++nt) {
            int oh = oh0 + nt * 2 + (lr >> 3), ow = ow0 + (lr & 7);
            #pragma unroll
            for (int reg = 0; reg < 4; ++reg) {
                int o = wave * 64 + m * 16 + lk * 4 + reg;
                out[(((size_t)b * COUT + o) * HW + oh) * HW + ow] = acc[m][nt][reg];
            }
        }
#undef STAGE_W
}

extern "C" void kernel_launch(void* const* d_in, const int* in_sizes, int n_in,
                              void* d_out, int out_size, void* d_ws, size_t ws_size,
                              hipStream_t stream) {
    const float* x   = (const float*)d_in[0];
    const float* kw  = (const float*)d_in[1];
    const float* fcw = (const float*)d_in[2];
    const float* fcb = (const float*)d_in[3];
    float* out = (float*)d_out;

    char* ws = (char*)d_ws;
    float* gap  = (float*)(ws + 0);                        //  32768 B
    float* rout = (float*)(ws + 32768);                    //   1024 B
    unsigned short* cmb = (unsigned short*)(ws + 33792);   // 37748736 B
    unsigned short* xtp = (unsigned short*)(ws + 33792 + 37748736); // 55107584 B

    hipMemsetAsync(gap, 0, BATCH * CIN * sizeof(float), stream);
    transpose_kernel<<<dim3(HP, 8, BATCH), 256, 0, stream>>>(x, xtp, gap);
    routing_kernel<<<1, 256, 0, stream>>>(gap, fcw, fcb, rout);
    combine_kernel<<<dim3(COUT, 4), 256, 0, stream>>>(kw, rout, cmb);
    conv_kernel<<<dim3(896), 256, 0, stream>>>(xtp, cmb, out);
}